// Round 5
// baseline (1675.064 us; speedup 1.0000x reference)
//
#include <hip/hip_runtime.h>
#include <hip/hip_bf16.h>
#include <stdint.h>

#define LROW 25600
#define NCH 256
#define LN_EPS 1e-5f

typedef float f32x4 __attribute__((ext_vector_type(4)));
typedef __bf16 bf16x8 __attribute__((ext_vector_type(8)));

__device__ __forceinline__ bf16x8 cvt8(f32x4 a, f32x4 b) {
  bf16x8 r;
  r[0] = (__bf16)a[0]; r[1] = (__bf16)a[1]; r[2] = (__bf16)a[2]; r[3] = (__bf16)a[3];
  r[4] = (__bf16)b[0]; r[5] = (__bf16)b[1]; r[6] = (__bf16)b[2]; r[7] = (__bf16)b[3];
  return r;
}

// raw barrier: drains LDS ops only, leaves prefetched global loads in flight
__device__ __forceinline__ void wg_bar() {
  asm volatile("s_waitcnt lgkmcnt(0)\n\ts_barrier" ::: "memory");
}

// ---------------------------------------------------------------------------
// Kernel A v5: 256 wgs = 8 batches x 32 k-slices (25 chunks of K=32 each).
// Each wg computes BOTH G (q x k) and Gkk (k x k) 256x256 tiles for its
// slice: q,k each fetched from HBM exactly once; k B-fragments shared by
// both MFMA streams. 1024 thr, 16 waves (4x4), accG+accK = 128 VGPR.
// bf16 double-buffered LDS (64KB), ONE barrier/chunk, reg prefetch.
// FULL: plain stores to per-slice partials (NO atomics). Fallback: atomics.
// ---------------------------------------------------------------------------
template <int FULL>
__global__ __launch_bounds__(1024, 4) void gram_k(
    const float* __restrict__ qg, const float* __restrict__ kg,
    float* __restrict__ P0,   // FULL: partials base; else G
    float* __restrict__ P1,   // FULL: unused;        else Gkk
    float* __restrict__ sq, float* __restrict__ sk) {
  __shared__ __align__(16) __bf16 lq[2][256 * 32];
  __shared__ __align__(16) __bf16 lk[2][256 * 32];

  const int bid = blockIdx.x;
  const int b = bid >> 5, s = bid & 31;
  const int c0 = s * 25;      // 800 chunks / 32 slices = 25 exactly
  const int nc = 25;

  const int tid = threadIdx.x;
  const int w = tid >> 6, lane = tid & 63;
  const int wr = w >> 2, wc = w & 3;
  const int lr = lane & 15, g = lane >> 4;

  // staging: thread owns (row rS = tid>>2, 8-float unit q4 = tid&3)
  const int rS = tid >> 2, q4 = tid & 3;
  const float* gq = qg + (size_t)b * NCH * LROW + (size_t)rS * LROW + q4 * 8;
  const float* gk = kg + (size_t)b * NCH * LROW + (size_t)rS * LROW + q4 * 8;
  const int offS = rS * 32 + ((q4 ^ (rS & 3)) * 8);

  const f32x4 zero = {0.f, 0.f, 0.f, 0.f};
  f32x4 accG[4][4], accK[4][4];
#pragma unroll
  for (int i = 0; i < 4; ++i)
#pragma unroll
    for (int j = 0; j < 4; ++j) { accG[i][j] = zero; accK[i][j] = zero; }

  float rsq = 0.f, rsk = 0.f;
  f32x4 bA[4], bB[4];

  auto LOADG = [&](int c, f32x4* d) {
    const float* pq = gq + (size_t)c * 32;
    d[0] = *(const f32x4*)pq;
    d[1] = *(const f32x4*)(pq + 4);
    const float* pk = gk + (size_t)c * 32;
    d[2] = *(const f32x4*)pk;
    d[3] = *(const f32x4*)(pk + 4);
  };
  auto WRITE = [&](f32x4* d, int buf) {
#pragma unroll
    for (int e = 0; e < 4; ++e) {
      rsq += d[0][e] + d[1][e];
      rsk += d[2][e] + d[3][e];
    }
    *(bf16x8*)(&lq[buf][offS]) = cvt8(d[0], d[1]);
    *(bf16x8*)(&lk[buf][offS]) = cvt8(d[2], d[3]);
  };
  auto COMPUTE = [&](int buf) {
    bf16x8 aq[4], ak[4];
#pragma unroll
    for (int i = 0; i < 4; ++i) {
      const int row = wr * 64 + i * 16 + lr;
      const int off = row * 32 + ((g ^ (row & 3)) * 8);
      aq[i] = *(const bf16x8*)(&lq[buf][off]);
      ak[i] = *(const bf16x8*)(&lk[buf][off]);
    }
#pragma unroll
    for (int j = 0; j < 4; ++j) {
      const int row = wc * 64 + j * 16 + lr;
      const int off = row * 32 + ((g ^ (row & 3)) * 8);
      bf16x8 bk = *(const bf16x8*)(&lk[buf][off]);
#pragma unroll
      for (int i = 0; i < 4; ++i) {
        accG[i][j] = __builtin_amdgcn_mfma_f32_16x16x32_bf16(aq[i], bk, accG[i][j], 0, 0, 0);
        accK[i][j] = __builtin_amdgcn_mfma_f32_16x16x32_bf16(ak[i], bk, accK[i][j], 0, 0, 0);
      }
    }
  };

  LOADG(c0 + 0, bA);
  LOADG(c0 + 1, bB);
  int cc = 0;
  for (; cc + 2 <= nc; cc += 2) {
    // chunk cc (buf 0): write -> barrier -> prefetch cc+2 -> compute
    WRITE(bA, 0);
    wg_bar();
    if (cc + 2 < nc) LOADG(c0 + cc + 2, bA);
    COMPUTE(0);
    // chunk cc+1 (buf 1)
    WRITE(bB, 1);
    wg_bar();
    if (cc + 3 < nc) LOADG(c0 + cc + 3, bB);
    COMPUTE(1);
  }
  if (cc < nc) { WRITE(bA, 0); wg_bar(); COMPUTE(0); }

  // row sums: reduce across the 4 lanes sharing a row, then one atomic each
  rsq += __shfl_xor(rsq, 1); rsq += __shfl_xor(rsq, 2);
  rsk += __shfl_xor(rsk, 1); rsk += __shfl_xor(rsk, 2);
  if (q4 == 0) {
    atomicAdd(sq + b * NCH + rS, rsq);
    atomicAdd(sk + b * NCH + rS, rsk);
  }

  if (FULL) {
    // plain stores to per-(b,slice) partials: [G 65536][Gkk 65536]
    float* Gout = P0 + (size_t)(b * 32 + s) * 131072;
#pragma unroll
    for (int i = 0; i < 4; ++i)
#pragma unroll
      for (int j = 0; j < 4; ++j) {
        const int col = wc * 64 + j * 16 + lr;
        const int row0 = wr * 64 + i * 16 + g * 4;
#pragma unroll
        for (int r = 0; r < 4; ++r) {
          Gout[(size_t)(row0 + r) * 256 + col] = accG[i][j][r];
          Gout[65536 + (size_t)(row0 + r) * 256 + col] = accK[i][j][r];
        }
      }
  } else {
    float* Gd = P0 + (size_t)b * 65536;
    float* Gkkd = P1 + (size_t)b * 65536;
#pragma unroll
    for (int i = 0; i < 4; ++i)
#pragma unroll
      for (int j = 0; j < 4; ++j) {
        const int col = wc * 64 + j * 16 + lr;
        const int row0 = wr * 64 + i * 16 + g * 4;
#pragma unroll
        for (int r = 0; r < 4; ++r) {
          atomicAdd(&Gd[(size_t)(row0 + r) * 256 + col], accG[i][j][r]);
          atomicAdd(&Gkkd[(size_t)(row0 + r) * 256 + col], accK[i][j][r]);
        }
      }
  }
}

// ---------------------------------------------------------------------------
// reduce partials: G[b] = sum_s Pp[b][s][0:64K], Gkk[b] = sum_s Pp[b][s][64K:]
// ---------------------------------------------------------------------------
__global__ __launch_bounds__(256) void reduce_k(
    const float* __restrict__ Pp, float* __restrict__ G, float* __restrict__ Gkk) {
  const int f = (blockIdx.x * 256 + threadIdx.x) * 4;  // float index, < 8*131072
  const int b = f >> 17, r = f & 131071;
  f32x4 a = {0.f, 0.f, 0.f, 0.f};
#pragma unroll
  for (int si = 0; si < 32; ++si)
    a += *(const f32x4*)(Pp + (size_t)(b * 32 + si) * 131072 + r);
  if (r < 65536) *(f32x4*)(G + (size_t)b * 65536 + r) = a;
  else *(f32x4*)(Gkk + (size_t)b * 65536 + (r - 65536)) = a;
}

// ---------------------------------------------------------------------------
// Kernel B1 (r3-proven): scores -> softmax -> M = A*Wv_h, cvec = A*bv_h
// ---------------------------------------------------------------------------
__global__ __launch_bounds__(256) void attn_k(
    const float* __restrict__ G, const float* __restrict__ sq,
    const float* __restrict__ sk,
    const float* __restrict__ Wq, const float* __restrict__ bq,
    const float* __restrict__ Wk, const float* __restrict__ bk,
    const float* __restrict__ Wv, const float* __restrict__ bv,
    float* __restrict__ M, float* __restrict__ cvec) {
  __shared__ float Wql[32][257];
  __shared__ float Wkl[32][257];
  __shared__ float QGl[32][257];
  __shared__ float Sl[32][33];
  __shared__ float Al[32][33];
  __shared__ float ul[32], wl[32];
  const int b = blockIdx.x >> 3, h = blockIdx.x & 7;
  const int t = threadIdx.x;
  const float* Gb = G + (size_t)b * 65536;

  for (int i = 0; i < 32; ++i) {
    int idx = i * 256 + t;
    int d = idx >> 8, c = idx & 255;
    Wql[d][c] = Wq[(h * 32 + d) * 256 + c];
    Wkl[d][c] = Wk[(h * 32 + d) * 256 + c];
  }
  __syncthreads();
  {
    float a[32];
#pragma unroll
    for (int d = 0; d < 32; ++d) a[d] = 0.f;
    for (int c = 0; c < 256; ++c) {
      float gv = Gb[c * 256 + t];
#pragma unroll
      for (int d = 0; d < 32; ++d) a[d] += Wql[d][c] * gv;
    }
    for (int d = 0; d < 32; ++d) QGl[d][t] = a[d];
  }
  if (t < 32) {
    float u = 0.f, wv = 0.f;
    for (int c = 0; c < 256; ++c) {
      u += Wql[t][c] * sq[b * 256 + c];
      wv += Wkl[t][c] * sk[b * 256 + c];
    }
    ul[t] = u; wl[t] = wv;
  }
  __syncthreads();
  for (int i = 0; i < 4; ++i) {
    int idx = i * 256 + t;
    int d = idx >> 5, e = idx & 31;
    float sv = 0.f;
    for (int c = 0; c < 256; ++c) sv += QGl[d][c] * Wkl[e][c];
    float bqd = bq[h * 32 + d], bke = bk[h * 32 + e];
    Sl[d][e] = (sv + ul[d] * bke + bqd * wl[e] + 25600.f * bqd * bke) * (1.f / 16.f);
  }
  __syncthreads();
  if (t < 32) {
    float m = -1e30f;
    for (int e = 0; e < 32; ++e) m = fmaxf(m, Sl[t][e]);
    float ssum = 0.f;
    for (int e = 0; e < 32; ++e) { float pp = __expf(Sl[t][e] - m); Al[t][e] = pp; ssum += pp; }
    float is = 1.f / ssum;
    for (int e = 0; e < 32; ++e) Al[t][e] *= is;
  }
  __syncthreads();
  {
    float a[32];
#pragma unroll
    for (int d = 0; d < 32; ++d) a[d] = 0.f;
    for (int e = 0; e < 32; ++e) {
      float wv = Wv[(h * 32 + e) * 256 + t];
#pragma unroll
      for (int d = 0; d < 32; ++d) a[d] += Al[d][e] * wv;
    }
    for (int d = 0; d < 32; ++d) M[((size_t)b * 256 + h * 32 + d) * 256 + t] = a[d];
  }
  if (t < 32) {
    float cv = 0.f;
    for (int e = 0; e < 32; ++e) cv += Al[t][e] * bv[h * 32 + e];
    cvec[b * 256 + h * 32 + t] = cv;
  }
}

// ---------------------------------------------------------------------------
// Kernel B2 (r3-proven): LN stats via quadratic form qf[c] = M Gkk M^T diag
// ---------------------------------------------------------------------------
__global__ __launch_bounds__(256) void stats_k(
    const float* __restrict__ Gkk, const float* __restrict__ M,
    const float* __restrict__ sk, const float* __restrict__ cvec,
    float* __restrict__ mu, float* __restrict__ inv) {
  __shared__ float Ml[32][257];
  __shared__ float Ql[32][257];
  const int b = blockIdx.x >> 3, cb = blockIdx.x & 7;
  const int t = threadIdx.x;
  const float* Gk = Gkk + (size_t)b * 65536;
  for (int i = 0; i < 32; ++i) {
    int idx = i * 256 + t;
    Ml[idx >> 8][idx & 255] = M[((size_t)b * 256 + cb * 32 + (idx >> 8)) * 256 + (idx & 255)];
  }
  __syncthreads();
  {
    float a[32];
#pragma unroll
    for (int c = 0; c < 32; ++c) a[c] = 0.f;
    for (int cc = 0; cc < 256; ++cc) {
      float gv = Gk[cc * 256 + t];
#pragma unroll
      for (int c = 0; c < 32; ++c) a[c] += Ml[c][cc] * gv;
    }
    for (int c = 0; c < 32; ++c) Ql[c][t] = a[c];
  }
  __syncthreads();
  if (t < 32) {
    float qf = 0.f, msk = 0.f;
    for (int j = 0; j < 256; ++j) {
      qf += Ql[t][j] * Ml[t][j];
      msk += Ml[t][j] * sk[b * 256 + j];
    }
    int c = cb * 32 + t;
    float cv = cvec[b * 256 + c];
    float muv = msk * (1.f / 25600.f) + cv;
    float sum2 = qf + 2.f * cv * msk + 25600.f * cv * cv;
    float var = sum2 * (1.f / 25600.f) - muv * muv;
    mu[b * 256 + c] = muv;
    inv[b * 256 + c] = rsqrtf(var + LN_EPS);
  }
}

// ---------------------------------------------------------------------------
// Kernel B3 (r3-proven): P = (Wo o inv) M (bf16), t1, wsum
// ---------------------------------------------------------------------------
__global__ __launch_bounds__(256) void pmat_k(
    const float* __restrict__ M, const float* __restrict__ Wo,
    const float* __restrict__ inv, const float* __restrict__ cvec,
    const float* __restrict__ mu, __bf16* __restrict__ Pb,
    float* __restrict__ t1, float* __restrict__ wsum) {
  __shared__ float Wol[32][257];
  __shared__ float invl[256];
  const int b = blockIdx.x >> 3, ob = blockIdx.x & 7;
  const int t = threadIdx.x;
  invl[t] = inv[b * 256 + t];
  __syncthreads();
  for (int i = 0; i < 32; ++i) {
    int idx = i * 256 + t;
    int o = idx >> 8, c = idx & 255;
    Wol[o][c] = Wo[(ob * 32 + o) * 256 + c] * invl[c];
  }
  __syncthreads();
  {
    float a[32];
#pragma unroll
    for (int o = 0; o < 32; ++o) a[o] = 0.f;
    for (int c = 0; c < 256; ++c) {
      float m = M[((size_t)b * 256 + c) * 256 + t];
#pragma unroll
      for (int o = 0; o < 32; ++o) a[o] += Wol[o][c] * m;
    }
    for (int o = 0; o < 32; ++o)
      Pb[((size_t)b * 256 + ob * 32 + o) * 256 + t] = (__bf16)a[o];
  }
  if (t < 32) {
    float s1 = 0.f, s2 = 0.f;
    for (int c = 0; c < 256; ++c) {
      s1 += Wol[t][c] * (cvec[b * 256 + c] - mu[b * 256 + c]);
      s2 += Wo[(ob * 32 + t) * 256 + c];
    }
    t1[b * 256 + ob * 32 + t] = s1;
    wsum[b * 256 + ob * 32 + t] = s2;
  }
}

// ---------------------------------------------------------------------------
// Kernel C v5: out = gamma*(P key + t1) + beta*wsum + bo.
// 3200 wgs (b x 64-l tile), 512 thr, 8 waves (4o x 2l), Bt 32KB -> 4 wg/CU.
// Stage: 2 lanes/row x 128B contiguous; LDS swizzle XORs l&31 into the
// 16B c-unit index (write-side bank spread; read-side stays bijective).
// ---------------------------------------------------------------------------
__global__ __launch_bounds__(512, 8) void outf_k(
    const float* __restrict__ key, const __bf16* __restrict__ Pb,
    const float* __restrict__ t1, const float* __restrict__ wsum,
    const float* __restrict__ bo, const float* __restrict__ gamma,
    const float* __restrict__ beta, float* __restrict__ out) {
  __shared__ __align__(16) __bf16 Bt[64 * 256];  // [l][c-swizzled], 32KB
  const int bid = blockIdx.x;
  const int b = bid / 400, lt = bid % 400, l0 = lt * 64;
  const int tid = threadIdx.x, w = tid >> 6, lane = tid & 63;
  const int wr = w >> 1, wc = w & 1;
  const int lr = lane & 15, g = lane >> 4;
  const float* Kb = key + (size_t)b * NCH * LROW;

  // stage: thread = (row c = tid>>1, half u0 = tid&1): 8 x f32x4 = 128B of row
  {
    const int c = tid >> 1, u0 = tid & 1;
    const int cu = c >> 3, ce2 = (c & 7) * 2;
    const float* src = Kb + (size_t)c * LROW + l0 + u0 * 32;
#pragma unroll
    for (int x = 0; x < 8; ++x) {
      f32x4 v = *(const f32x4*)(src + x * 4);
#pragma unroll
      for (int j = 0; j < 4; ++j) {
        const int l = u0 * 32 + x * 4 + j;
        *(__bf16*)((char*)Bt + l * 512 + ((cu ^ (l & 31)) << 4) + ce2) = (__bf16)v[j];
      }
    }
  }
  __syncthreads();

  const f32x4 zero = {0.f, 0.f, 0.f, 0.f};
  f32x4 acc[4][2];
#pragma unroll
  for (int i = 0; i < 4; ++i)
#pragma unroll
    for (int j = 0; j < 2; ++j) acc[i][j] = zero;

  const __bf16* Pbase = Pb + (size_t)b * 65536;
#pragma unroll
  for (int ks = 0; ks < 8; ++ks) {
    bf16x8 af[4];
#pragma unroll
    for (int i = 0; i < 4; ++i) {
      const int row = wr * 64 + i * 16 + lr;
      af[i] = *(const bf16x8*)(Pbase + (size_t)row * 256 + ks * 32 + g * 8);
    }
#pragma unroll
    for (int j = 0; j < 2; ++j) {
      const int col = wc * 32 + j * 16 + lr;
      bf16x8 bfj = *(const bf16x8*)((const char*)Bt + col * 512 +
                                    (((ks * 4 + g) ^ (col & 31)) << 4));
#pragma unroll
      for (int i = 0; i < 4; ++i)
        acc[i][j] = __builtin_amdgcn_mfma_f32_16x16x32_bf16(af[i], bfj, acc[i][j], 0, 0, 0);
    }
  }

  float t1r[4][4], wsr[4][4], bor[4][4];
#pragma unroll
  for (int i = 0; i < 4; ++i)
#pragma unroll
    for (int r = 0; r < 4; ++r) {
      const int row = wr * 64 + i * 16 + g * 4 + r;
      t1r[i][r] = t1[b * 256 + row];
      wsr[i][r] = wsum[b * 256 + row];
      bor[i][r] = bo[row];
    }
#pragma unroll
  for (int j = 0; j < 2; ++j) {
    const int colg = l0 + wc * 32 + j * 16 + lr;
    const float gm = gamma[colg];
    const float bt = beta[colg];
#pragma unroll
    for (int i = 0; i < 4; ++i) {
      const int row0 = wr * 64 + i * 16 + g * 4;
#pragma unroll
      for (int r = 0; r < 4; ++r) {
        const int row = row0 + r;
        float v = gm * (acc[i][j][r] + t1r[i][r]) + bt * wsr[i][r] + bor[i][r];
        out[((size_t)b * 256 + row) * LROW + colg] = v;
      }
    }
  }
}

// ---------------------------------------------------------------------------
extern "C" void kernel_launch(void* const* d_in, const int* in_sizes, int n_in,
                              void* d_out, int out_size, void* d_ws, size_t ws_size,
                              hipStream_t stream) {
  const float* query = (const float*)d_in[0];
  const float* key   = (const float*)d_in[1];
  const float* Wq = (const float*)d_in[2];
  const float* bq = (const float*)d_in[3];
  const float* Wk = (const float*)d_in[4];
  const float* bk = (const float*)d_in[5];
  const float* Wv = (const float*)d_in[6];
  const float* bv = (const float*)d_in[7];
  const float* Wo = (const float*)d_in[8];
  const float* bo = (const float*)d_in[9];
  const float* gamma = (const float*)d_in[10];
  const float* beta  = (const float*)d_in[11];
  float* out = (float*)d_out;

  float* ws = (float*)d_ws;
  float* G    = ws;                  // 524288
  float* Gkk  = G + 524288;          // 524288
  float* sq   = Gkk + 524288;        // 2048
  float* sk   = sq + 2048;           // 2048
  float* M    = sk + 2048;           // 524288
  float* cvec = M + 524288;          // 2048
  float* mu   = cvec + 2048;         // 2048
  float* inv  = mu + 2048;           // 2048
  float* t1   = inv + 2048;          // 2048
  float* wsum = t1 + 2048;           // 2048
  __bf16* Pb  = (__bf16*)(wsum + 2048);  // 524288 bf16 = 262144 floats
  // base end (floats): 3*524288 + 6*2048 + 262144 = 1847296
  float* Pp = ws + 1847296;          // 8*32*131072 = 33554432 floats (134MB)
  const size_t need = (size_t)(1847296 + 33554432) * 4;

  if (ws_size >= need) {
    hipMemsetAsync(sq, 0, 4096 * sizeof(float), stream);  // sq+sk only
    gram_k<1><<<256, 1024, 0, stream>>>(query, key, Pp, nullptr, sq, sk);
    reduce_k<<<1024, 256, 0, stream>>>(Pp, G, Gkk);
  } else {
    hipMemsetAsync(d_ws, 0, (size_t)1052672 * sizeof(float), stream);  // G,Gkk,sq,sk
    gram_k<0><<<256, 1024, 0, stream>>>(query, key, G, Gkk, sq, sk);
  }
  attn_k<<<64, 256, 0, stream>>>(G, sq, sk, Wq, bq, Wk, bk, Wv, bv, M, cvec);
  stats_k<<<64, 256, 0, stream>>>(Gkk, M, sk, cvec, mu, inv);
  pmat_k<<<64, 256, 0, stream>>>(M, Wo, inv, cvec, mu, Pb, t1, wsum);
  outf_k<<<3200, 512, 0, stream>>>(key, Pb, t1, wsum, bo, gamma, beta, out);
}

// Round 6
// 1032.251 us; speedup vs baseline: 1.6227x; 1.6227x over previous
//
#include <hip/hip_runtime.h>
#include <hip/hip_bf16.h>
#include <stdint.h>

#define LROW 25600
#define NCH 256
#define LN_EPS 1e-5f

typedef float f32x4 __attribute__((ext_vector_type(4)));
typedef __bf16 bf16x8 __attribute__((ext_vector_type(8)));

__device__ __forceinline__ bf16x8 cvt8(f32x4 a, f32x4 b) {
  bf16x8 r;
  r[0] = (__bf16)a[0]; r[1] = (__bf16)a[1]; r[2] = (__bf16)a[2]; r[3] = (__bf16)a[3];
  r[4] = (__bf16)b[0]; r[5] = (__bf16)b[1]; r[6] = (__bf16)b[2]; r[7] = (__bf16)b[3];
  return r;
}

// raw barrier: drains LDS ops only, leaves prefetched global loads in flight
__device__ __forceinline__ void wg_bar() {
  asm volatile("s_waitcnt lgkmcnt(0)\n\ts_barrier" ::: "memory");
}

// ---------------------------------------------------------------------------
// Kernel A v6: Grams via 768 wgs = 96 groups (8b x 12 kslices) x 8 tiles
// (4 G-quadrants + 4 Gkk-quadrants, 128x128 each). Groups XCD-pinned:
// all 8 tiles of a group + 12 groups co-resident per XCD -> q/k panels
// shared via L2/L3. 256 thr (4 waves 2x2, 64x64/wave, acc=64), 3 wgs/CU
// (r4-proven register shape: ~84 VGPR + 64 acc <= 170 cap).
// bf16 double-buffered LDS (32KB), 1 barrier/chunk, 2-chunk reg prefetch.
// FULL: plain stores to per-(group) partials (NO matrix atomics).
// ---------------------------------------------------------------------------
template <int FULL>
__global__ __launch_bounds__(256, 3) void gram_k(
    const float* __restrict__ qg, const float* __restrict__ kg,
    float* __restrict__ P0,   // FULL: partials base; else G
    float* __restrict__ P1,   // FULL: unused;        else Gkk
    float* __restrict__ sq, float* __restrict__ sk) {
  __shared__ __align__(16) __bf16 lA[2][128 * 32];
  __shared__ __align__(16) __bf16 lB[2][128 * 32];

  const int bid = blockIdx.x;
  const int xcd = bid & 7, s2 = bid >> 3;   // consecutive bids round-robin XCDs
  const int tile = s2 & 7, gslot = s2 >> 3; // gslot 0..11
  const int g = gslot * 8 + xcd;            // group 0..95, fixed XCD per group
  const int b = g / 12, ks = g % 12;
  const int mat = tile >> 2;                // 0: G = q x k, 1: Gkk = k x k
  const int ri = (tile >> 1) & 1, ci = tile & 1;
  const int c0 = (800 * ks) / 12, c1 = (800 * (ks + 1)) / 12;
  const int nc = c1 - c0;                   // 66 or 67 chunks of K=32

  const int tid = threadIdx.x;
  const int w = tid >> 6, lane = tid & 63;
  const int wr = w >> 1, wc = w & 1;
  const int lr = lane & 15, gq = lane >> 4;

  const float* Abase = (mat ? kg : qg) + (size_t)b * NCH * LROW + (size_t)(ri * 128) * LROW;
  const float* Bbase = kg + (size_t)b * NCH * LROW + (size_t)(ci * 128) * LROW;

  // staging: thread owns (row rowS = tid>>1, 16-float half h = tid&1)
  const int rowS = tid >> 1, h = tid & 1;
  const float* Ap = Abase + (size_t)rowS * LROW + h * 16 + (size_t)c0 * 32;
  const float* Bp = Bbase + (size_t)rowS * LROW + h * 16 + (size_t)c0 * 32;
  const int swz = rowS & 3;
  const int d0 = rowS * 32 + (((2 * h) ^ swz) * 8);
  const int d1 = rowS * 32 + (((2 * h + 1) ^ swz) * 8);

  const f32x4 zero = {0.f, 0.f, 0.f, 0.f};
  f32x4 acc[4][4];
#pragma unroll
  for (int i = 0; i < 4; ++i)
#pragma unroll
    for (int j = 0; j < 4; ++j) acc[i][j] = zero;

  float rsum = 0.f;
  f32x4 bA[8], bB[8];

  auto LOADG = [&](int c, f32x4* d) {
    const float* pa = Ap + (size_t)c * 32;
#pragma unroll
    for (int i = 0; i < 4; ++i) d[i] = *(const f32x4*)(pa + i * 4);
    const float* pb = Bp + (size_t)c * 32;
#pragma unroll
    for (int i = 0; i < 4; ++i) d[4 + i] = *(const f32x4*)(pb + i * 4);
  };
  auto WRITE = [&](f32x4* d, int buf) {
#pragma unroll
    for (int e = 0; e < 4; ++e)
      rsum += d[0][e] + d[1][e] + d[2][e] + d[3][e];  // A-panel row partial
    *(bf16x8*)(&lA[buf][d0]) = cvt8(d[0], d[1]);
    *(bf16x8*)(&lA[buf][d1]) = cvt8(d[2], d[3]);
    *(bf16x8*)(&lB[buf][d0]) = cvt8(d[4], d[5]);
    *(bf16x8*)(&lB[buf][d1]) = cvt8(d[6], d[7]);
  };
  auto COMPUTE = [&](int buf) {
    bf16x8 af[4];
#pragma unroll
    for (int i = 0; i < 4; ++i) {
      const int row = wr * 64 + i * 16 + lr;
      af[i] = *(const bf16x8*)(&lA[buf][row * 32 + ((gq ^ (row & 3)) * 8)]);
    }
#pragma unroll
    for (int j = 0; j < 4; ++j) {
      const int row = wc * 64 + j * 16 + lr;
      bf16x8 bfj = *(const bf16x8*)(&lB[buf][row * 32 + ((gq ^ (row & 3)) * 8)]);
#pragma unroll
      for (int i = 0; i < 4; ++i)
        acc[i][j] = __builtin_amdgcn_mfma_f32_16x16x32_bf16(af[i], bfj, acc[i][j], 0, 0, 0);
    }
  };

  LOADG(0, bA);
  LOADG(1, bB);
  int cc = 0;
  for (; cc + 2 <= nc; cc += 2) {
    WRITE(bA, 0);
    wg_bar();
    if (cc + 2 < nc) LOADG(cc + 2, bA);
    COMPUTE(0);
    WRITE(bB, 1);
    wg_bar();
    if (cc + 3 < nc) LOADG(cc + 3, bB);
    COMPUTE(1);
  }
  if (cc < nc) { WRITE(bA, 0); wg_bar(); COMPUTE(0); }

  // row sums: pair-reduce (two threads per row), one atomic per row,
  // counted once per (mat, row): only ci==0 tiles contribute.
  rsum += __shfl_xor(rsum, 1);
  if (h == 0 && ci == 0)
    atomicAdd((mat ? sk : sq) + b * NCH + ri * 128 + rowS, rsum);

  if (FULL) {
    // plain coalesced stores to per-group partials: [(b,ks)][mat][256x256]
    float* Gout = P0 + ((size_t)(b * 12 + ks) * 2 + mat) * 65536;
#pragma unroll
    for (int i = 0; i < 4; ++i)
#pragma unroll
      for (int r = 0; r < 4; ++r) {
        const int rr = ri * 128 + wr * 64 + i * 16 + gq * 4 + r;
#pragma unroll
        for (int j = 0; j < 4; ++j) {
          const int col = ci * 128 + wc * 64 + j * 16 + lr;
          Gout[(size_t)rr * 256 + col] = acc[i][j][r];
        }
      }
  } else {
    float* Gout = (mat ? P1 : P0) + (size_t)b * 65536;
#pragma unroll
    for (int i = 0; i < 4; ++i)
#pragma unroll
      for (int r = 0; r < 4; ++r) {
        const int rr = ri * 128 + wr * 64 + i * 16 + gq * 4 + r;
#pragma unroll
        for (int j = 0; j < 4; ++j) {
          const int col = ci * 128 + wc * 64 + j * 16 + lr;
          atomicAdd(&Gout[(size_t)rr * 256 + col], acc[i][j][r]);
        }
      }
  }
}

// ---------------------------------------------------------------------------
// reduce partials over 12 kslices: G[b] / Gkk[b]
// ---------------------------------------------------------------------------
__global__ __launch_bounds__(256) void reduce_k(
    const float* __restrict__ Pp, float* __restrict__ G, float* __restrict__ Gkk) {
  const int f = (blockIdx.x * 256 + threadIdx.x) * 4;  // < 8*2*65536 = 1048576
  const int b = f >> 17, rem = f & 131071;
  const int mat = rem >> 16, r = rem & 65535;
  f32x4 a = {0.f, 0.f, 0.f, 0.f};
#pragma unroll
  for (int ks = 0; ks < 12; ++ks)
    a += *(const f32x4*)(Pp + ((size_t)(b * 12 + ks) * 2 + mat) * 65536 + r);
  float* dst = (mat ? Gkk : G) + (size_t)b * 65536 + r;
  *(f32x4*)dst = a;
}

// ---------------------------------------------------------------------------
// Kernel B1: scores -> softmax -> M = A*Wv_h, cvec (r3 + unrolled loads)
// ---------------------------------------------------------------------------
__global__ __launch_bounds__(256) void attn_k(
    const float* __restrict__ G, const float* __restrict__ sq,
    const float* __restrict__ sk,
    const float* __restrict__ Wq, const float* __restrict__ bq,
    const float* __restrict__ Wk, const float* __restrict__ bk,
    const float* __restrict__ Wv, const float* __restrict__ bv,
    float* __restrict__ M, float* __restrict__ cvec) {
  __shared__ float Wql[32][257];
  __shared__ float Wkl[32][257];
  __shared__ float QGl[32][257];
  __shared__ float Sl[32][33];
  __shared__ float Al[32][33];
  __shared__ float ul[32], wl[32];
  const int b = blockIdx.x >> 3, hh = blockIdx.x & 7;
  const int t = threadIdx.x;
  const float* Gb = G + (size_t)b * 65536;

  for (int i = 0; i < 32; ++i) {
    int idx = i * 256 + t;
    int d = idx >> 8, c = idx & 255;
    Wql[d][c] = Wq[(hh * 32 + d) * 256 + c];
    Wkl[d][c] = Wk[(hh * 32 + d) * 256 + c];
  }
  __syncthreads();
  {
    float a[32];
#pragma unroll
    for (int d = 0; d < 32; ++d) a[d] = 0.f;
#pragma unroll 8
    for (int c = 0; c < 256; ++c) {
      float gv = Gb[c * 256 + t];
#pragma unroll
      for (int d = 0; d < 32; ++d) a[d] += Wql[d][c] * gv;
    }
    for (int d = 0; d < 32; ++d) QGl[d][t] = a[d];
  }
  if (t < 32) {
    float u = 0.f, wv = 0.f;
#pragma unroll 8
    for (int c = 0; c < 256; ++c) {
      u += Wql[t][c] * sq[b * 256 + c];
      wv += Wkl[t][c] * sk[b * 256 + c];
    }
    ul[t] = u; wl[t] = wv;
  }
  __syncthreads();
  for (int i = 0; i < 4; ++i) {
    int idx = i * 256 + t;
    int d = idx >> 5, e = idx & 31;
    float sv = 0.f;
#pragma unroll 8
    for (int c = 0; c < 256; ++c) sv += QGl[d][c] * Wkl[e][c];
    float bqd = bq[hh * 32 + d], bke = bk[hh * 32 + e];
    Sl[d][e] = (sv + ul[d] * bke + bqd * wl[e] + 25600.f * bqd * bke) * (1.f / 16.f);
  }
  __syncthreads();
  if (t < 32) {
    float m = -1e30f;
    for (int e = 0; e < 32; ++e) m = fmaxf(m, Sl[t][e]);
    float ssum = 0.f;
    for (int e = 0; e < 32; ++e) { float pp = __expf(Sl[t][e] - m); Al[t][e] = pp; ssum += pp; }
    float is = 1.f / ssum;
    for (int e = 0; e < 32; ++e) Al[t][e] *= is;
  }
  __syncthreads();
  {
    float a[32];
#pragma unroll
    for (int d = 0; d < 32; ++d) a[d] = 0.f;
#pragma unroll 4
    for (int e = 0; e < 32; ++e) {
      float wv = Wv[(hh * 32 + e) * 256 + t];
#pragma unroll
      for (int d = 0; d < 32; ++d) a[d] += Al[d][e] * wv;
    }
    for (int d = 0; d < 32; ++d) M[((size_t)b * 256 + hh * 32 + d) * 256 + t] = a[d];
  }
  if (t < 32) {
    float cv = 0.f;
    for (int e = 0; e < 32; ++e) cv += Al[t][e] * bv[hh * 32 + e];
    cvec[b * 256 + hh * 32 + t] = cv;
  }
}

// ---------------------------------------------------------------------------
// Kernel B2: LN stats via quadratic form (r3 + unrolled loads)
// ---------------------------------------------------------------------------
__global__ __launch_bounds__(256) void stats_k(
    const float* __restrict__ Gkk, const float* __restrict__ M,
    const float* __restrict__ sk, const float* __restrict__ cvec,
    float* __restrict__ mu, float* __restrict__ inv) {
  __shared__ float Ml[32][257];
  __shared__ float Ql[32][257];
  const int b = blockIdx.x >> 3, cb = blockIdx.x & 7;
  const int t = threadIdx.x;
  const float* Gk = Gkk + (size_t)b * 65536;
  for (int i = 0; i < 32; ++i) {
    int idx = i * 256 + t;
    Ml[idx >> 8][idx & 255] = M[((size_t)b * 256 + cb * 32 + (idx >> 8)) * 256 + (idx & 255)];
  }
  __syncthreads();
  {
    float a[32];
#pragma unroll
    for (int c = 0; c < 32; ++c) a[c] = 0.f;
#pragma unroll 8
    for (int cc = 0; cc < 256; ++cc) {
      float gv = Gk[cc * 256 + t];
#pragma unroll
      for (int c = 0; c < 32; ++c) a[c] += Ml[c][cc] * gv;
    }
    for (int c = 0; c < 32; ++c) Ql[c][t] = a[c];
  }
  __syncthreads();
  if (t < 32) {
    float qf = 0.f, msk = 0.f;
#pragma unroll 8
    for (int j = 0; j < 256; ++j) {
      qf += Ql[t][j] * Ml[t][j];
      msk += Ml[t][j] * sk[b * 256 + j];
    }
    int c = cb * 32 + t;
    float cv = cvec[b * 256 + c];
    float muv = msk * (1.f / 25600.f) + cv;
    float sum2 = qf + 2.f * cv * msk + 25600.f * cv * cv;
    float var = sum2 * (1.f / 25600.f) - muv * muv;
    mu[b * 256 + c] = muv;
    inv[b * 256 + c] = rsqrtf(var + LN_EPS);
  }
}

// ---------------------------------------------------------------------------
// Kernel B3: P = (Wo o inv) M (bf16), t1, wsum (r3 + unrolled loads)
// ---------------------------------------------------------------------------
__global__ __launch_bounds__(256) void pmat_k(
    const float* __restrict__ M, const float* __restrict__ Wo,
    const float* __restrict__ inv, const float* __restrict__ cvec,
    const float* __restrict__ mu, __bf16* __restrict__ Pb,
    float* __restrict__ t1, float* __restrict__ wsum) {
  __shared__ float Wol[32][257];
  __shared__ float invl[256];
  const int b = blockIdx.x >> 3, ob = blockIdx.x & 7;
  const int t = threadIdx.x;
  invl[t] = inv[b * 256 + t];
  __syncthreads();
  for (int i = 0; i < 32; ++i) {
    int idx = i * 256 + t;
    int o = idx >> 8, c = idx & 255;
    Wol[o][c] = Wo[(ob * 32 + o) * 256 + c] * invl[c];
  }
  __syncthreads();
  {
    float a[32];
#pragma unroll
    for (int o = 0; o < 32; ++o) a[o] = 0.f;
#pragma unroll 8
    for (int c = 0; c < 256; ++c) {
      float m = M[((size_t)b * 256 + c) * 256 + t];
#pragma unroll
      for (int o = 0; o < 32; ++o) a[o] += Wol[o][c] * m;
    }
    for (int o = 0; o < 32; ++o)
      Pb[((size_t)b * 256 + ob * 32 + o) * 256 + t] = (__bf16)a[o];
  }
  if (t < 32) {
    float s1 = 0.f, s2 = 0.f;
#pragma unroll 8
    for (int c = 0; c < 256; ++c) {
      s1 += Wol[t][c] * (cvec[b * 256 + c] - mu[b * 256 + c]);
      s2 += Wo[(ob * 32 + t) * 256 + c];
    }
    t1[b * 256 + ob * 32 + t] = s1;
    wsum[b * 256 + ob * 32 + t] = s2;
  }
}

// ---------------------------------------------------------------------------
// Kernel C: out = gamma*(P key + t1) + beta*wsum + bo (fused LN + conv).
// 1600 wgs batch-pinned to XCDs (b = bid&7), 512 thr, 8 waves (4x2),
// 64KB LDS -> 2 wg/CU. Lean epilogue (per-row scalar reloads, low VGPR).
// ---------------------------------------------------------------------------
__global__ __launch_bounds__(512, 4) void outf_k(
    const float* __restrict__ key, const __bf16* __restrict__ Pb,
    const float* __restrict__ t1, const float* __restrict__ wsum,
    const float* __restrict__ bo, const float* __restrict__ gamma,
    const float* __restrict__ beta, float* __restrict__ out) {
  __shared__ __align__(16) __bf16 Bt[128 * 256];  // [l][c], XOR-swizzled, 64KB
  const int bid = blockIdx.x;
  const int b = bid & 7, lt = bid >> 3, l0 = lt * 128;  // batch -> XCD pin
  const int tid = threadIdx.x, w = tid >> 6, lane = tid & 63;
  const int wr = w >> 1, wc = w & 1;
  const int lr = lane & 15, g = lane >> 4;
  const float* Kb = key + (size_t)b * NCH * LROW;

  // stage: thread = (channel c, l-half seg); 16x f32x4 contiguous per lane
  {
    const int c = tid & 255, seg = tid >> 8;
    const int uc = c >> 3, cb2 = (c & 7) * 2;
    const float* src = Kb + (size_t)c * LROW + l0 + seg * 64;
#pragma unroll
    for (int i = 0; i < 16; ++i) {
      f32x4 v = *(const f32x4*)(src + i * 4);
#pragma unroll
      for (int j = 0; j < 4; ++j) {
        const int l = seg * 64 + i * 4 + j;
        *(__bf16*)((char*)Bt + l * 512 + ((uc ^ (l & 7)) << 4) + cb2) = (__bf16)v[j];
      }
    }
  }
  __syncthreads();

  const f32x4 zero = {0.f, 0.f, 0.f, 0.f};
  f32x4 acc[4][4];
#pragma unroll
  for (int i = 0; i < 4; ++i)
#pragma unroll
    for (int j = 0; j < 4; ++j) acc[i][j] = zero;

  const __bf16* Pbase = Pb + (size_t)b * 65536;
#pragma unroll
  for (int ks = 0; ks < 8; ++ks) {
    bf16x8 af[4];
#pragma unroll
    for (int i = 0; i < 4; ++i) {
      const int row = wr * 64 + i * 16 + lr;
      af[i] = *(const bf16x8*)(Pbase + (size_t)row * 256 + ks * 32 + g * 8);
    }
#pragma unroll
    for (int j = 0; j < 4; ++j) {
      const int col = wc * 64 + j * 16 + lr;
      const int unit = ks * 4 + g;
      bf16x8 bfj = *(const bf16x8*)((const char*)Bt + col * 512 + ((unit ^ (col & 7)) << 4));
#pragma unroll
      for (int i = 0; i < 4; ++i)
        acc[i][j] = __builtin_amdgcn_mfma_f32_16x16x32_bf16(af[i], bfj, acc[i][j], 0, 0, 0);
    }
  }

  // lean epilogue: i/r outer (row scalars live briefly), j inner
#pragma unroll
  for (int i = 0; i < 4; ++i)
#pragma unroll
    for (int r = 0; r < 4; ++r) {
      const int row = wr * 64 + i * 16 + g * 4 + r;
      const float t1v = t1[b * 256 + row];
      const float wsv = wsum[b * 256 + row];
      const float bov = bo[row];
      const size_t ro = ((size_t)b * 256 + row) * LROW + l0;
#pragma unroll
      for (int j = 0; j < 4; ++j) {
        const int cl = wc * 64 + j * 16 + lr;
        out[ro + cl] = gamma[l0 + cl] * (acc[i][j][r] + t1v) + beta[l0 + cl] * wsv + bov;
      }
    }
}

// ---------------------------------------------------------------------------
extern "C" void kernel_launch(void* const* d_in, const int* in_sizes, int n_in,
                              void* d_out, int out_size, void* d_ws, size_t ws_size,
                              hipStream_t stream) {
  const float* query = (const float*)d_in[0];
  const float* key   = (const float*)d_in[1];
  const float* Wq = (const float*)d_in[2];
  const float* bq = (const float*)d_in[3];
  const float* Wk = (const float*)d_in[4];
  const float* bk = (const float*)d_in[5];
  const float* Wv = (const float*)d_in[6];
  const float* bv = (const float*)d_in[7];
  const float* Wo = (const float*)d_in[8];
  const float* bo = (const float*)d_in[9];
  const float* gamma = (const float*)d_in[10];
  const float* beta  = (const float*)d_in[11];
  float* out = (float*)d_out;

  float* ws = (float*)d_ws;
  float* G    = ws;                  // 524288
  float* Gkk  = G + 524288;          // 524288
  float* sq   = Gkk + 524288;        // 2048
  float* sk   = sq + 2048;           // 2048
  float* M    = sk + 2048;           // 524288
  float* cvec = M + 524288;          // 2048
  float* mu   = cvec + 2048;         // 2048
  float* inv  = mu + 2048;           // 2048
  float* t1   = inv + 2048;          // 2048
  float* wsum = t1 + 2048;           // 2048
  __bf16* Pb  = (__bf16*)(wsum + 2048);  // 524288 bf16 = 262144 floats
  // base end (floats): 3*524288 + 6*2048 + 262144 = 1849344
  float* Pp = ws + 1849344;          // 8*12*2*65536 = 12582912 floats (50MB)
  const size_t need = (size_t)(1849344 + 12582912) * 4;

  if (ws_size >= need) {
    hipMemsetAsync(sq, 0, 4096 * sizeof(float), stream);  // sq+sk only
    gram_k<1><<<768, 256, 0, stream>>>(query, key, Pp, nullptr, sq, sk);
    reduce_k<<<1024, 256, 0, stream>>>(Pp, G, Gkk);
  } else {
    hipMemsetAsync(d_ws, 0, (size_t)1052672 * sizeof(float), stream);  // G,Gkk,sq,sk
    gram_k<0><<<768, 256, 0, stream>>>(query, key, G, Gkk, sq, sk);
  }
  attn_k<<<64, 256, 0, stream>>>(G, sq, sk, Wq, bq, Wk, bk, Wv, bv, M, cvec);
  stats_k<<<64, 256, 0, stream>>>(Gkk, M, sk, cvec, mu, inv);
  pmat_k<<<64, 256, 0, stream>>>(M, Wo, inv, cvec, mu, Pb, t1, wsum);
  outf_k<<<1600, 512, 0, stream>>>(key, Pb, t1, wsum, bo, gamma, beta, out);
}

// Round 7
// 1027.980 us; speedup vs baseline: 1.6295x; 1.0042x over previous
//
#include <hip/hip_runtime.h>
#include <hip/hip_bf16.h>
#include <stdint.h>

#define LROW 25600
#define NCH 256
#define LN_EPS 1e-5f

typedef float f32x4 __attribute__((ext_vector_type(4)));
typedef __bf16 bf16x8 __attribute__((ext_vector_type(8)));

__device__ __forceinline__ bf16x8 cvt8(f32x4 a, f32x4 b) {
  bf16x8 r;
  r[0] = (__bf16)a[0]; r[1] = (__bf16)a[1]; r[2] = (__bf16)a[2]; r[3] = (__bf16)a[3];
  r[4] = (__bf16)b[0]; r[5] = (__bf16)b[1]; r[6] = (__bf16)b[2]; r[7] = (__bf16)b[3];
  return r;
}

// raw barrier: drains LDS ops only, leaves prefetched global loads in flight
__device__ __forceinline__ void wg_bar() {
  asm volatile("s_waitcnt lgkmcnt(0)\n\ts_barrier" ::: "memory");
}

// ---------------------------------------------------------------------------
// Kernel A v7: Grams via 768 wgs = 96 groups (8b x 12 kslices) x 8 tiles
// (4 G-quadrants + 4 Gkk-quadrants, 128x128). Groups XCD-pinned. 256 thr
// (4 waves 2x2, 64x64/wave, acc=64), 3 wgs/CU. bf16 dbuf LDS (32KB) with
// r4's PROVEN conflict-free swizzle ((row>>1)&3). Epilogue: plain stores
// to per-group partials living in D_OUT (no ws_size dependence, NO atomics).
// ---------------------------------------------------------------------------
__global__ __launch_bounds__(256, 3) void gram_k(
    const float* __restrict__ qg, const float* __restrict__ kg,
    float* __restrict__ Pp,   // partials: [(b*12+ks)*2+mat][256x256] (in d_out)
    float* __restrict__ sq, float* __restrict__ sk) {
  __shared__ __align__(16) __bf16 lA[2][128 * 32];
  __shared__ __align__(16) __bf16 lB[2][128 * 32];

  const int bid = blockIdx.x;
  const int xcd = bid & 7, s2 = bid >> 3;   // consecutive bids round-robin XCDs
  const int tile = s2 & 7, gslot = s2 >> 3; // gslot 0..11
  const int g = gslot * 8 + xcd;            // group 0..95, fixed XCD per group
  const int b = g / 12, ks = g % 12;
  const int mat = tile >> 2;                // 0: G = q x k, 1: Gkk = k x k
  const int ri = (tile >> 1) & 1, ci = tile & 1;
  const int c0 = (800 * ks) / 12, c1 = (800 * (ks + 1)) / 12;
  const int nc = c1 - c0;                   // 66 or 67 chunks of K=32

  const int tid = threadIdx.x;
  const int w = tid >> 6, lane = tid & 63;
  const int wr = w >> 1, wc = w & 1;
  const int lr = lane & 15, gq = lane >> 4;

  const float* Abase = (mat ? kg : qg) + (size_t)b * NCH * LROW + (size_t)(ri * 128) * LROW;
  const float* Bbase = kg + (size_t)b * NCH * LROW + (size_t)(ci * 128) * LROW;

  // staging: thread owns (row rowS = tid>>1, 16-float half h = tid&1)
  const int rowS = tid >> 1, h = tid & 1;
  const float* Ap = Abase + (size_t)rowS * LROW + h * 16 + (size_t)c0 * 32;
  const float* Bp = Bbase + (size_t)rowS * LROW + h * 16 + (size_t)c0 * 32;
  const int swz = (rowS >> 1) & 3;  // r4-proven: matches read gq^((row>>1)&3)
  const int d0 = rowS * 32 + (((2 * h) ^ swz) * 8);
  const int d1 = rowS * 32 + (((2 * h + 1) ^ swz) * 8);

  const f32x4 zero = {0.f, 0.f, 0.f, 0.f};
  f32x4 acc[4][4];
#pragma unroll
  for (int i = 0; i < 4; ++i)
#pragma unroll
    for (int j = 0; j < 4; ++j) acc[i][j] = zero;

  float rsum = 0.f;
  f32x4 bA[8], bB[8];

  auto LOADG = [&](int c, f32x4* d) {
    const float* pa = Ap + (size_t)c * 32;
#pragma unroll
    for (int i = 0; i < 4; ++i) d[i] = *(const f32x4*)(pa + i * 4);
    const float* pb = Bp + (size_t)c * 32;
#pragma unroll
    for (int i = 0; i < 4; ++i) d[4 + i] = *(const f32x4*)(pb + i * 4);
  };
  auto WRITE = [&](f32x4* d, int buf) {
#pragma unroll
    for (int e = 0; e < 4; ++e)
      rsum += d[0][e] + d[1][e] + d[2][e] + d[3][e];  // A-panel row partial
    *(bf16x8*)(&lA[buf][d0]) = cvt8(d[0], d[1]);
    *(bf16x8*)(&lA[buf][d1]) = cvt8(d[2], d[3]);
    *(bf16x8*)(&lB[buf][d0]) = cvt8(d[4], d[5]);
    *(bf16x8*)(&lB[buf][d1]) = cvt8(d[6], d[7]);
  };
  auto COMPUTE = [&](int buf) {
    bf16x8 af[4];
#pragma unroll
    for (int i = 0; i < 4; ++i) {
      const int row = wr * 64 + i * 16 + lr;
      af[i] = *(const bf16x8*)(&lA[buf][row * 32 + ((gq ^ ((row >> 1) & 3)) * 8)]);
    }
#pragma unroll
    for (int j = 0; j < 4; ++j) {
      const int row = wc * 64 + j * 16 + lr;
      bf16x8 bfj = *(const bf16x8*)(&lB[buf][row * 32 + ((gq ^ ((row >> 1) & 3)) * 8)]);
#pragma unroll
      for (int i = 0; i < 4; ++i)
        acc[i][j] = __builtin_amdgcn_mfma_f32_16x16x32_bf16(af[i], bfj, acc[i][j], 0, 0, 0);
    }
  };

  LOADG(0, bA);
  LOADG(1, bB);
  int cc = 0;
  for (; cc + 2 <= nc; cc += 2) {
    WRITE(bA, 0);
    wg_bar();
    if (cc + 2 < nc) LOADG(cc + 2, bA);
    COMPUTE(0);
    WRITE(bB, 1);
    wg_bar();
    if (cc + 3 < nc) LOADG(cc + 3, bB);
    COMPUTE(1);
  }
  if (cc < nc) { WRITE(bA, 0); wg_bar(); COMPUTE(0); }

  // row sums: pair-reduce (two threads per row), one atomic per row,
  // counted once per (mat, row): only ci==0 tiles contribute. (~100K atomics)
  rsum += __shfl_xor(rsum, 1);
  if (h == 0 && ci == 0)
    atomicAdd((mat ? sk : sq) + b * NCH + ri * 128 + rowS, rsum);

  // plain coalesced stores to per-group partials in d_out (single writer)
  float* Gout = Pp + ((size_t)(b * 12 + ks) * 2 + mat) * 65536;
#pragma unroll
  for (int i = 0; i < 4; ++i)
#pragma unroll
    for (int r = 0; r < 4; ++r) {
      const int rr = ri * 128 + wr * 64 + i * 16 + gq * 4 + r;
#pragma unroll
      for (int j = 0; j < 4; ++j) {
        const int col = ci * 128 + wc * 64 + j * 16 + lr;
        Gout[(size_t)rr * 256 + col] = acc[i][j][r];
      }
    }
}

// ---------------------------------------------------------------------------
// reduce partials over 12 kslices: G[b] / Gkk[b]
// ---------------------------------------------------------------------------
__global__ __launch_bounds__(256) void reduce_k(
    const float* __restrict__ Pp, float* __restrict__ G, float* __restrict__ Gkk) {
  const int f = (blockIdx.x * 256 + threadIdx.x) * 4;  // < 8*2*65536 = 1048576
  const int b = f >> 17, rem = f & 131071;
  const int mat = rem >> 16, r = rem & 65535;
  f32x4 a = {0.f, 0.f, 0.f, 0.f};
#pragma unroll
  for (int ks = 0; ks < 12; ++ks)
    a += *(const f32x4*)(Pp + ((size_t)(b * 12 + ks) * 2 + mat) * 65536 + r);
  float* dst = (mat ? Gkk : G) + (size_t)b * 65536 + r;
  *(f32x4*)dst = a;
}

// ---------------------------------------------------------------------------
// Kernel B1: scores -> softmax -> M = A*Wv_h, cvec
// ---------------------------------------------------------------------------
__global__ __launch_bounds__(256) void attn_k(
    const float* __restrict__ G, const float* __restrict__ sq,
    const float* __restrict__ sk,
    const float* __restrict__ Wq, const float* __restrict__ bq,
    const float* __restrict__ Wk, const float* __restrict__ bk,
    const float* __restrict__ Wv, const float* __restrict__ bv,
    float* __restrict__ M, float* __restrict__ cvec) {
  __shared__ float Wql[32][257];
  __shared__ float Wkl[32][257];
  __shared__ float QGl[32][257];
  __shared__ float Sl[32][33];
  __shared__ float Al[32][33];
  __shared__ float ul[32], wl[32];
  const int b = blockIdx.x >> 3, hh = blockIdx.x & 7;
  const int t = threadIdx.x;
  const float* Gb = G + (size_t)b * 65536;

  for (int i = 0; i < 32; ++i) {
    int idx = i * 256 + t;
    int d = idx >> 8, c = idx & 255;
    Wql[d][c] = Wq[(hh * 32 + d) * 256 + c];
    Wkl[d][c] = Wk[(hh * 32 + d) * 256 + c];
  }
  __syncthreads();
  {
    float a[32];
#pragma unroll
    for (int d = 0; d < 32; ++d) a[d] = 0.f;
#pragma unroll 8
    for (int c = 0; c < 256; ++c) {
      float gv = Gb[c * 256 + t];
#pragma unroll
      for (int d = 0; d < 32; ++d) a[d] += Wql[d][c] * gv;
    }
    for (int d = 0; d < 32; ++d) QGl[d][t] = a[d];
  }
  if (t < 32) {
    float u = 0.f, wv = 0.f;
#pragma unroll 8
    for (int c = 0; c < 256; ++c) {
      u += Wql[t][c] * sq[b * 256 + c];
      wv += Wkl[t][c] * sk[b * 256 + c];
    }
    ul[t] = u; wl[t] = wv;
  }
  __syncthreads();
  for (int i = 0; i < 4; ++i) {
    int idx = i * 256 + t;
    int d = idx >> 5, e = idx & 31;
    float sv = 0.f;
#pragma unroll 8
    for (int c = 0; c < 256; ++c) sv += QGl[d][c] * Wkl[e][c];
    float bqd = bq[hh * 32 + d], bke = bk[hh * 32 + e];
    Sl[d][e] = (sv + ul[d] * bke + bqd * wl[e] + 25600.f * bqd * bke) * (1.f / 16.f);
  }
  __syncthreads();
  if (t < 32) {
    float m = -1e30f;
    for (int e = 0; e < 32; ++e) m = fmaxf(m, Sl[t][e]);
    float ssum = 0.f;
    for (int e = 0; e < 32; ++e) { float pp = __expf(Sl[t][e] - m); Al[t][e] = pp; ssum += pp; }
    float is = 1.f / ssum;
    for (int e = 0; e < 32; ++e) Al[t][e] *= is;
  }
  __syncthreads();
  {
    float a[32];
#pragma unroll
    for (int d = 0; d < 32; ++d) a[d] = 0.f;
#pragma unroll 4
    for (int e = 0; e < 32; ++e) {
      float wv = Wv[(hh * 32 + e) * 256 + t];
#pragma unroll
      for (int d = 0; d < 32; ++d) a[d] += Al[d][e] * wv;
    }
    for (int d = 0; d < 32; ++d) M[((size_t)b * 256 + hh * 32 + d) * 256 + t] = a[d];
  }
  if (t < 32) {
    float cv = 0.f;
    for (int e = 0; e < 32; ++e) cv += Al[t][e] * bv[hh * 32 + e];
    cvec[b * 256 + hh * 32 + t] = cv;
  }
}

// ---------------------------------------------------------------------------
// Kernel B2: LN stats via quadratic form qf[c] = M Gkk M^T diag
// ---------------------------------------------------------------------------
__global__ __launch_bounds__(256) void stats_k(
    const float* __restrict__ Gkk, const float* __restrict__ M,
    const float* __restrict__ sk, const float* __restrict__ cvec,
    float* __restrict__ mu, float* __restrict__ inv) {
  __shared__ float Ml[32][257];
  __shared__ float Ql[32][257];
  const int b = blockIdx.x >> 3, cb = blockIdx.x & 7;
  const int t = threadIdx.x;
  const float* Gk = Gkk + (size_t)b * 65536;
  for (int i = 0; i < 32; ++i) {
    int idx = i * 256 + t;
    Ml[idx >> 8][idx & 255] = M[((size_t)b * 256 + cb * 32 + (idx >> 8)) * 256 + (idx & 255)];
  }
  __syncthreads();
  {
    float a[32];
#pragma unroll
    for (int c = 0; c < 32; ++c) a[c] = 0.f;
#pragma unroll 8
    for (int cc = 0; cc < 256; ++cc) {
      float gv = Gk[cc * 256 + t];
#pragma unroll
      for (int c = 0; c < 32; ++c) a[c] += Ml[c][cc] * gv;
    }
    for (int c = 0; c < 32; ++c) Ql[c][t] = a[c];
  }
  __syncthreads();
  if (t < 32) {
    float qf = 0.f, msk = 0.f;
#pragma unroll 8
    for (int j = 0; j < 256; ++j) {
      qf += Ql[t][j] * Ml[t][j];
      msk += Ml[t][j] * sk[b * 256 + j];
    }
    int c = cb * 32 + t;
    float cv = cvec[b * 256 + c];
    float muv = msk * (1.f / 25600.f) + cv;
    float sum2 = qf + 2.f * cv * msk + 25600.f * cv * cv;
    float var = sum2 * (1.f / 25600.f) - muv * muv;
    mu[b * 256 + c] = muv;
    inv[b * 256 + c] = rsqrtf(var + LN_EPS);
  }
}

// ---------------------------------------------------------------------------
// Kernel B3: P = (Wo o inv) M (bf16), t1, wsum
// ---------------------------------------------------------------------------
__global__ __launch_bounds__(256) void pmat_k(
    const float* __restrict__ M, const float* __restrict__ Wo,
    const float* __restrict__ inv, const float* __restrict__ cvec,
    const float* __restrict__ mu, __bf16* __restrict__ Pb,
    float* __restrict__ t1, float* __restrict__ wsum) {
  __shared__ float Wol[32][257];
  __shared__ float invl[256];
  const int b = blockIdx.x >> 3, ob = blockIdx.x & 7;
  const int t = threadIdx.x;
  invl[t] = inv[b * 256 + t];
  __syncthreads();
  for (int i = 0; i < 32; ++i) {
    int idx = i * 256 + t;
    int o = idx >> 8, c = idx & 255;
    Wol[o][c] = Wo[(ob * 32 + o) * 256 + c] * invl[c];
  }
  __syncthreads();
  {
    float a[32];
#pragma unroll
    for (int o = 0; o < 32; ++o) a[o] = 0.f;
#pragma unroll 8
    for (int c = 0; c < 256; ++c) {
      float m = M[((size_t)b * 256 + c) * 256 + t];
#pragma unroll
      for (int o = 0; o < 32; ++o) a[o] += Wol[o][c] * m;
    }
    for (int o = 0; o < 32; ++o)
      Pb[((size_t)b * 256 + ob * 32 + o) * 256 + t] = (__bf16)a[o];
  }
  if (t < 32) {
    float s1 = 0.f, s2 = 0.f;
#pragma unroll 8
    for (int c = 0; c < 256; ++c) {
      s1 += Wol[t][c] * (cvec[b * 256 + c] - mu[b * 256 + c]);
      s2 += Wo[(ob * 32 + t) * 256 + c];
    }
    t1[b * 256 + ob * 32 + t] = s1;
    wsum[b * 256 + ob * 32 + t] = s2;
  }
}

// ---------------------------------------------------------------------------
// Kernel C: out = gamma*(P key + t1) + beta*wsum + bo (fused LN + conv).
// 1600 wgs batch-pinned to XCDs (b = bid&7), 512 thr, 8 waves (4x2),
// 64KB LDS -> 2 wg/CU. Lean epilogue. Overwrites the d_out scratch LAST.
// ---------------------------------------------------------------------------
__global__ __launch_bounds__(512, 4) void outf_k(
    const float* __restrict__ key, const __bf16* __restrict__ Pb,
    const float* __restrict__ t1, const float* __restrict__ wsum,
    const float* __restrict__ bo, const float* __restrict__ gamma,
    const float* __restrict__ beta, float* __restrict__ out) {
  __shared__ __align__(16) __bf16 Bt[128 * 256];  // [l][c], XOR-swizzled, 64KB
  const int bid = blockIdx.x;
  const int b = bid & 7, lt = bid >> 3, l0 = lt * 128;  // batch -> XCD pin
  const int tid = threadIdx.x, w = tid >> 6, lane = tid & 63;
  const int wr = w >> 1, wc = w & 1;
  const int lr = lane & 15, g = lane >> 4;
  const float* Kb = key + (size_t)b * NCH * LROW;

  // stage: thread = (channel c, l-half seg); 16x f32x4 contiguous per lane
  {
    const int c = tid & 255, seg = tid >> 8;
    const int uc = c >> 3, cb2 = (c & 7) * 2;
    const float* src = Kb + (size_t)c * LROW + l0 + seg * 64;
#pragma unroll
    for (int i = 0; i < 16; ++i) {
      f32x4 v = *(const f32x4*)(src + i * 4);
#pragma unroll
      for (int j = 0; j < 4; ++j) {
        const int l = seg * 64 + i * 4 + j;
        *(__bf16*)((char*)Bt + l * 512 + ((uc ^ (l & 7)) << 4) + cb2) = (__bf16)v[j];
      }
    }
  }
  __syncthreads();

  const f32x4 zero = {0.f, 0.f, 0.f, 0.f};
  f32x4 acc[4][4];
#pragma unroll
  for (int i = 0; i < 4; ++i)
#pragma unroll
    for (int j = 0; j < 4; ++j) acc[i][j] = zero;

  const __bf16* Pbase = Pb + (size_t)b * 65536;
#pragma unroll
  for (int ks = 0; ks < 8; ++ks) {
    bf16x8 af[4];
#pragma unroll
    for (int i = 0; i < 4; ++i) {
      const int row = wr * 64 + i * 16 + lr;
      af[i] = *(const bf16x8*)(Pbase + (size_t)row * 256 + ks * 32 + g * 8);
    }
#pragma unroll
    for (int j = 0; j < 4; ++j) {
      const int col = wc * 64 + j * 16 + lr;
      const int unit = ks * 4 + g;
      bf16x8 bfj = *(const bf16x8*)((const char*)Bt + col * 512 + ((unit ^ (col & 7)) << 4));
#pragma unroll
      for (int i = 0; i < 4; ++i)
        acc[i][j] = __builtin_amdgcn_mfma_f32_16x16x32_bf16(af[i], bfj, acc[i][j], 0, 0, 0);
    }
  }

  // lean epilogue: i/r outer (row scalars live briefly), j inner
#pragma unroll
  for (int i = 0; i < 4; ++i)
#pragma unroll
    for (int r = 0; r < 4; ++r) {
      const int row = wr * 64 + i * 16 + g * 4 + r;
      const float t1v = t1[b * 256 + row];
      const float wsv = wsum[b * 256 + row];
      const float bov = bo[row];
      const size_t ro = ((size_t)b * 256 + row) * LROW + l0;
#pragma unroll
      for (int j = 0; j < 4; ++j) {
        const int cl = wc * 64 + j * 16 + lr;
        out[ro + cl] = gamma[l0 + cl] * (acc[i][j][r] + t1v) + beta[l0 + cl] * wsv + bov;
      }
    }
}

// ---------------------------------------------------------------------------
extern "C" void kernel_launch(void* const* d_in, const int* in_sizes, int n_in,
                              void* d_out, int out_size, void* d_ws, size_t ws_size,
                              hipStream_t stream) {
  const float* query = (const float*)d_in[0];
  const float* key   = (const float*)d_in[1];
  const float* Wq = (const float*)d_in[2];
  const float* bq = (const float*)d_in[3];
  const float* Wk = (const float*)d_in[4];
  const float* bk = (const float*)d_in[5];
  const float* Wv = (const float*)d_in[6];
  const float* bv = (const float*)d_in[7];
  const float* Wo = (const float*)d_in[8];
  const float* bo = (const float*)d_in[9];
  const float* gamma = (const float*)d_in[10];
  const float* beta  = (const float*)d_in[11];
  float* out = (float*)d_out;

  // Workspace: base layout only (7.4MB — safe for any plausible ws_size)
  float* ws = (float*)d_ws;
  float* G    = ws;                  // 524288
  float* Gkk  = G + 524288;          // 524288
  float* sq   = Gkk + 524288;        // 2048
  float* sk   = sq + 2048;           // 2048
  float* M    = sk + 2048;           // 524288 (16MB total so far... fits)
  float* cvec = M + 524288;          // 2048
  float* mu   = cvec + 2048;         // 2048
  float* inv  = mu + 2048;           // 2048
  float* t1   = inv + 2048;          // 2048
  float* wsum = t1 + 2048;           // 2048
  __bf16* Pb  = (__bf16*)(wsum + 2048);  // 524288 bf16

  // Gram partials live in D_OUT (50MB of its 209MB) — overwritten by outf_k
  // at the very end; each partial element has exactly ONE writer.
  float* Pp = out;

  hipMemsetAsync(sq, 0, 4096 * sizeof(float), stream);  // sq+sk (row-sum atomics)
  gram_k<<<768, 256, 0, stream>>>(query, key, Pp, sq, sk);
  reduce_k<<<1024, 256, 0, stream>>>(Pp, G, Gkk);
  attn_k<<<64, 256, 0, stream>>>(G, sq, sk, Wq, bq, Wk, bk, Wv, bv, M, cvec);
  stats_k<<<64, 256, 0, stream>>>(Gkk, M, sk, cvec, mu, inv);
  pmat_k<<<64, 256, 0, stream>>>(M, Wo, inv, cvec, mu, Pb, t1, wsum);
  outf_k<<<1600, 512, 0, stream>>>(key, Pb, t1, wsum, bo, gamma, beta, out);
}